// Round 1
// baseline (315.354 us; speedup 1.0000x reference)
//
#include <hip/hip_runtime.h>

// Problem constants
#define BB   4
#define CC   144
#define HW   4096      // 64*64
#define PTOT 16384     // BB*HW
#define EPSB 1e-5f

typedef __bf16 bf16;
typedef __bf16 bf16x8 __attribute__((ext_vector_type(8)));
typedef float  f32x4  __attribute__((ext_vector_type(4)));
typedef unsigned short U16;
typedef unsigned int   U32;
typedef U16 u16x8 __attribute__((ext_vector_type(8)));

#define MFMA __builtin_amdgcn_mfma_f32_16x16x32_bf16

// ---- workspace layout (bytes) ----
#define XN_OFF    0UL         // bf16 [4][144][64][64]          4,718,592
#define A1_OFF    4718592UL   // bf16 [16384][64][25]           52,428,800
#define A2_OFF    57147392UL  // bf16 [16384][576]              18,874,368
#define WINF_OFF  76021760UL  // bf16 frag [4][5][64][8]        20,480
#define W1F_OFF   76042240UL  // bf16 frag [4][18][64][8]       73,728
#define W2F_OFF   76115968UL  // bf16 frag [4][18][64][8]       73,728
#define WOUTF_OFF 76189696UL  // bf16 frag [9][2][64][8]        18,432
#define BNP_OFF   76208128UL  // f32 [672]: s_in,t_in,s1,t1,s2,t2 (64 each), s_out,t_out (144 each)

// ------------------------------------------------------------------
// K1: L2 normalize over channel dim, output bf16
// grid 256 (b*64+h), block 256 (64 w x 4 channel-quarters)
__global__ __launch_bounds__(256) void k_norm(const float* __restrict__ x,
                                              bf16* __restrict__ xn)
{
    __shared__ float red[4][64];
    int bh = blockIdx.x;
    int b = bh >> 6, h = bh & 63;
    int t = threadIdx.x, w = t & 63, cq = t >> 6;
    const float* px = x + ((size_t)b*CC)*HW + h*64 + w;
    float s = 0.f;
    for (int c = cq*36; c < cq*36 + 36; c++) { float v = px[c*HW]; s += v*v; }
    red[cq][w] = s;
    __syncthreads();
    float tot = red[0][w] + red[1][w] + red[2][w] + red[3][w];
    float inv = 1.f / fmaxf(sqrtf(tot), 1e-12f);
    bf16* po = xn + ((size_t)b*CC)*HW + h*64 + w;
    for (int c = cq*36; c < cq*36 + 36; c++) po[c*HW] = (bf16)(px[c*HW] * inv);
}

// ------------------------------------------------------------------
// K2: pack weights into MFMA A-fragment order + fold BN params
// frag value layout: F[mt][ks][lane][j] = W[o = mt*16 + (lane&15)][k = ks*32 + (lane>>4)*8 + j]
__global__ __launch_bounds__(256) void k_pack(
    const float* __restrict__ w_in, const float* __restrict__ w1,
    const float* __restrict__ w2,   const float* __restrict__ w_out,
    const float* g_in, const float* b_in, const float* m_in, const float* v_in,
    const float* g1,   const float* b1,   const float* m1,   const float* v1,
    const float* g2,   const float* b2,   const float* m2,   const float* v2,
    const float* g_out,const float* b_out,const float* m_out,const float* v_out,
    bf16* w_inf, bf16* w1f, bf16* w2f, bf16* w_outf, float* bnp)
{
    int t = blockIdx.x*256 + threadIdx.x;
    if (t < 10240) {                       // w_inf: K padded 144->160
        int e = t, j = e & 7, lane = (e >> 3) & 63, r = e >> 9;
        int ks = r % 5, mt = r / 5;
        int o = mt*16 + (lane & 15);
        int c = ks*32 + ((lane >> 4) << 3) + j;
        w_inf[e] = (c < 144) ? (bf16)w_in[o*144 + c] : (bf16)0.f;
    } else if (t < 47104) {                // w1f: K = 576 exact
        int e = t - 10240, j = e & 7, lane = (e >> 3) & 63, r = e >> 9;
        int ks = r % 18, mt = r / 18;
        int o = mt*16 + (lane & 15);
        int k = ks*32 + ((lane >> 4) << 3) + j;
        w1f[e] = (bf16)w1[o*576 + k];
    } else if (t < 83968) {                // w2f
        int e = t - 47104, j = e & 7, lane = (e >> 3) & 63, r = e >> 9;
        int ks = r % 18, mt = r / 18;
        int o = mt*16 + (lane & 15);
        int k = ks*32 + ((lane >> 4) << 3) + j;
        w2f[e] = (bf16)w2[o*576 + k];
    } else if (t < 93184) {                // w_outf: M=144 (9 mt), K=64 (2 ks)
        int e = t - 83968, j = e & 7, lane = (e >> 3) & 63, r = e >> 9;
        int ks = r & 1, mt = r >> 1;
        int o = mt*16 + (lane & 15);
        int c = ks*32 + ((lane >> 4) << 3) + j;
        w_outf[e] = (bf16)w_out[o*64 + c];
    } else if (t < 93856) {                // BN fold: s = g*rsqrt(v+eps), t = b - m*s
        int i = t - 93184;
        const float *g, *bb, *mm, *vv; int c; bool is_t;
        if (i < 128)      { g=g_in; bb=b_in; mm=m_in; vv=v_in; c=i&63;        is_t=i>=64;  }
        else if (i < 256) { g=g1;   bb=b1;   mm=m1;   vv=v1;   c=(i-128)&63;  is_t=i>=192; }
        else if (i < 384) { g=g2;   bb=b2;   mm=m2;   vv=v2;   c=(i-256)&63;  is_t=i>=320; }
        else              { int ii=i-384; g=g_out; bb=b_out; mm=m_out; vv=v_out;
                            c = ii % 144; is_t = ii >= 144; }
        float s = g[c] * rsqrtf(vv[c] + EPSB);
        bnp[i] = is_t ? (bb[c] - mm[c]*s) : s;
    }
}

// ------------------------------------------------------------------
// K3: stage 1 per position: Z1[64,25] = W_in(64x144) @ (center*patch)(144x25), BN+ReLU
// grid 16384 (one position per block), block 256 (4 waves = 4 m-tiles)
__global__ __launch_bounds__(256) void k_s1(const bf16* __restrict__ xn,
        const bf16* __restrict__ w_inf, const float* __restrict__ bnp,
        bf16* __restrict__ a1)
{
    __shared__ __align__(16) bf16 Bf[5120];   // B-frags [nt=2][ks=5][lane][8]
    __shared__ __align__(4)  bf16 zbuf[1600]; // a1 staging [c=64][kp=25]
    __shared__ float uLf[144];                // center channel vector
    int p = blockIdx.x;
    int b = p >> 12, hw = p & 4095, h = hw >> 6, w = hw & 63;
    int t = threadIdx.x;
    const bf16* xb = xn + (size_t)b*CC*HW;
    for (int c = t; c < 144; c += 256) uLf[c] = (float)xb[c*HW + hw];
    __syncthreads();
    for (int e = t; e < 5120; e += 256) {
        int j = e & 7, lane = (e >> 3) & 63, r = e >> 9;
        int ks = r % 5, nt = r / 5;
        int c  = ks*32 + ((lane >> 4) << 3) + j;
        int kp = nt*16 + (lane & 15);
        float val = 0.f;
        if (c < 144 && kp < 25) {
            int hh2 = h + kp/5 - 2, ww = w + kp%5 - 2;
            if (hh2 >= 0 && hh2 < 64 && ww >= 0 && ww < 64)
                val = (float)xb[c*HW + (hh2 << 6) + ww] * uLf[c];
        }
        Bf[e] = (bf16)val;
    }
    __syncthreads();
    int wid = t >> 6, lane = t & 63, quad = lane >> 4, col = lane & 15;
    f32x4 acc0 = {}, acc1 = {};
    #pragma unroll
    for (int ks = 0; ks < 5; ks++) {
        bf16x8 af = *(const bf16x8*)(w_inf + ((wid*5 + ks)*64 + lane)*8);
        bf16x8 b0 = *(const bf16x8*)(Bf + (ks*64 + lane)*8);
        bf16x8 b1 = *(const bf16x8*)(Bf + ((5 + ks)*64 + lane)*8);
        acc0 = MFMA(af, b0, acc0, 0, 0, 0);
        acc1 = MFMA(af, b1, acc1, 0, 0, 0);
    }
    #pragma unroll
    for (int r = 0; r < 4; r++) {
        int o = wid*16 + quad*4 + r;
        float s = bnp[o], tt = bnp[64 + o];
        zbuf[o*25 + col] = (bf16)fmaxf(acc0[r]*s + tt, 0.f);
        if (col < 9)
            zbuf[o*25 + 16 + col] = (bf16)fmaxf(acc1[r]*s + tt, 0.f);
    }
    __syncthreads();
    U32* dst = (U32*)(a1 + (size_t)p*1600);
    const U32* src = (const U32*)zbuf;
    for (int i = t; i < 800; i += 256) dst[i] = src[i];
}

// ------------------------------------------------------------------
// K4: stage 2 as GEMM M=64, K=576 (c*9+ij), N=147456 (p*9+rs), 128-col tiles
// im2col gather from a1 via LUT; double-buffered LDS B; A-frags from L2-hot w1f
__global__ __launch_bounds__(256) void k_s2(const bf16* __restrict__ w1f,
        const bf16* __restrict__ a1, const float* __restrict__ bnp,
        bf16* __restrict__ a2)
{
    __shared__ __align__(16) U16 Bc[2][12288]; // [nt=8][kc=3][lane][8]
    __shared__ U32 tAR[128];                   // p*1600 + r*5+s
    __shared__ U32 tO[128];                    // p*576 + rs
    __shared__ U16 koff[576];                  // k -> c*25 + (i*5+jj)
    int t = threadIdx.x;
    int wid = t >> 6, lane = t & 63, quad = lane >> 4, col16 = lane & 15;
    int n0 = blockIdx.x * 128;
    if (t < 128) {
        int j2 = n0 + t;
        int pp = j2 / 9, rs = j2 - 9*pp;
        int r = rs/3, s = rs - 3*r;
        tAR[t] = (U32)pp*1600 + (U32)(r*5 + s);
        tO[t]  = (U32)pp*576 + (U32)rs;
    }
    for (int k = t; k < 576; k += 256) {
        int c = k/9, ij = k - 9*c;
        koff[k] = (U16)(c*25 + ij + 2*(ij/3));
    }
    __syncthreads();
    const U16* a1u = (const U16*)a1;
    f32x4 acc[4][2] = {};
    U16 g[6][8];

#define GATHER(CH) do { \
    _Pragma("unroll") \
    for (int u = 0; u < 6; u++) { \
        int fr = t + (u << 8); \
        int lf = fr & 63, rem = fr >> 6; \
        int kc = rem % 3, nt = rem / 3; \
        int colg = (nt << 4) + (lf & 15); \
        int k0 = ((CH)*3 + kc)*32 + ((lf >> 4) << 3); \
        u16x8 ko = *(const u16x8*)&koff[k0]; \
        U32 base = tAR[colg]; \
        _Pragma("unroll") \
        for (int j = 0; j < 8; j++) g[u][j] = a1u[base + ko[j]]; \
    } } while(0)

#define COMMITB(BUF) do { \
    _Pragma("unroll") \
    for (int u = 0; u < 6; u++) { \
        int fr = t + (u << 8); \
        u16x8 vv; \
        _Pragma("unroll") \
        for (int j = 0; j < 8; j++) vv[j] = g[u][j]; \
        *(u16x8*)&Bc[BUF][fr << 3] = vv; \
    } } while(0)

    GATHER(0);
    COMMITB(0);
    for (int ch = 0; ch < 6; ch++) {
        __syncthreads();                 // Bc[ch&1] ready; prior mfma on other buf done
        if (ch < 5) GATHER(ch + 1);      // overlap next gather with this chunk's MFMAs
        #pragma unroll
        for (int kc = 0; kc < 3; kc++) {
            int ksg = ch*3 + kc;
            bf16x8 b0 = *(const bf16x8*)&Bc[ch & 1][(((2*wid  )*3 + kc)*64 + lane) << 3];
            bf16x8 b1 = *(const bf16x8*)&Bc[ch & 1][(((2*wid+1)*3 + kc)*64 + lane) << 3];
            #pragma unroll
            for (int mt = 0; mt < 4; mt++) {
                bf16x8 af = *(const bf16x8*)(w1f + ((mt*18 + ksg)*64 + lane)*8);
                acc[mt][0] = MFMA(af, b0, acc[mt][0], 0, 0, 0);
                acc[mt][1] = MFMA(af, b1, acc[mt][1], 0, 0, 0);
            }
        }
        if (ch < 5) COMMITB((ch + 1) & 1);
    }
    // epilogue: BN + ReLU -> a2[p*576 + o*9 + rs]
    #pragma unroll
    for (int ntl = 0; ntl < 2; ntl++) {
        int col = (2*wid + ntl)*16 + col16;
        U32 obase = tO[col];
        #pragma unroll
        for (int mt = 0; mt < 4; mt++) {
            #pragma unroll
            for (int r = 0; r < 4; r++) {
                int o = mt*16 + quad*4 + r;
                float s = bnp[128 + o], tt = bnp[192 + o];
                a2[obase + o*9] = (bf16)fmaxf(acc[mt][ntl][r]*s + tt, 0.f);
            }
        }
    }
#undef GATHER
#undef COMMITB
}

// ------------------------------------------------------------------
// K5: stage 3 (64x576 @ per-position a2, N=64 cols = one image row) + BN/ReLU
//     -> LDS transpose -> stage 4 (144x64) + final BN -> fp32 out
// grid 256 (row blocks), block 256 (4 waves)
__global__ __launch_bounds__(256) void k_s34(const bf16* __restrict__ a2,
        const bf16* __restrict__ w2f, const bf16* __restrict__ w_outf,
        const float* __restrict__ bnp, float* __restrict__ out)
{
    __shared__ __align__(16) U16 v3[64*64];   // [col][cm]
    int t = threadIdx.x, wid = t >> 6, lane = t & 63, quad = lane >> 4, col16 = lane & 15;
    int p0 = blockIdx.x * 64;
    int b = p0 >> 12, hw0 = p0 & 4095;
    // stage 3: wave = m-tile, all 4 n-tiles; B-frags contiguous in a2
    f32x4 acc[4] = {};
    for (int ks = 0; ks < 18; ks++) {
        bf16x8 af = *(const bf16x8*)(w2f + ((wid*18 + ks)*64 + lane)*8);
        #pragma unroll
        for (int nt = 0; nt < 4; nt++) {
            int p = p0 + nt*16 + col16;
            bf16x8 bfr = *(const bf16x8*)(a2 + (size_t)p*576 + ks*32 + quad*8);
            acc[nt] = MFMA(af, bfr, acc[nt], 0, 0, 0);
        }
    }
    #pragma unroll
    for (int nt = 0; nt < 4; nt++) {
        int colA = nt*16 + col16;
        #pragma unroll
        for (int r = 0; r < 4; r++) {
            int o = wid*16 + quad*4 + r;
            float s = bnp[256 + o], tt = bnp[320 + o];
            bf16 yb = (bf16)fmaxf(acc[nt][r]*s + tt, 0.f);
            v3[colA*64 + o] = *(U16*)&yb;
        }
    }
    __syncthreads();
    // stage 4: M=144 (9 m-tiles split over 4 waves), K=64 (2 ksteps), N=64
    for (int mt = wid; mt < 9; mt += 4) {
        f32x4 accB[4] = {};
        #pragma unroll
        for (int ks = 0; ks < 2; ks++) {
            bf16x8 af = *(const bf16x8*)(w_outf + ((mt*2 + ks)*64 + lane)*8);
            #pragma unroll
            for (int nt = 0; nt < 4; nt++) {
                bf16x8 bfr = *(const bf16x8*)&v3[(nt*16 + col16)*64 + ks*32 + quad*8];
                accB[nt] = MFMA(af, bfr, accB[nt], 0, 0, 0);
            }
        }
        #pragma unroll
        for (int nt = 0; nt < 4; nt++) {
            #pragma unroll
            for (int r = 0; r < 4; r++) {
                int oc = mt*16 + quad*4 + r;
                float s = bnp[384 + oc], tt = bnp[528 + oc];
                out[((size_t)(b*144 + oc))*4096 + hw0 + nt*16 + col16] = accB[nt][r]*s + tt;
            }
        }
    }
}

// ------------------------------------------------------------------
extern "C" void kernel_launch(void* const* d_in, const int* in_sizes, int n_in,
                              void* d_out, int out_size, void* d_ws, size_t ws_size,
                              hipStream_t stream)
{
    const float* x     = (const float*)d_in[0];
    const float* w_in  = (const float*)d_in[1];
    const float* g_in  = (const float*)d_in[2];
    const float* b_in  = (const float*)d_in[3];
    const float* m_in  = (const float*)d_in[4];
    const float* v_in  = (const float*)d_in[5];
    const float* w1    = (const float*)d_in[6];
    const float* g1    = (const float*)d_in[7];
    const float* b1    = (const float*)d_in[8];
    const float* m1    = (const float*)d_in[9];
    const float* v1    = (const float*)d_in[10];
    const float* w2    = (const float*)d_in[11];
    const float* g2    = (const float*)d_in[12];
    const float* b2    = (const float*)d_in[13];
    const float* m2    = (const float*)d_in[14];
    const float* v2    = (const float*)d_in[15];
    const float* w_out = (const float*)d_in[16];
    const float* g_out = (const float*)d_in[17];
    const float* b_out = (const float*)d_in[18];
    const float* m_out = (const float*)d_in[19];
    const float* v_out = (const float*)d_in[20];
    float* out = (float*)d_out;

    char* ws = (char*)d_ws;
    bf16*  xn     = (bf16*)(ws + XN_OFF);
    bf16*  a1     = (bf16*)(ws + A1_OFF);
    bf16*  a2     = (bf16*)(ws + A2_OFF);
    bf16*  w_inf  = (bf16*)(ws + WINF_OFF);
    bf16*  w1f    = (bf16*)(ws + W1F_OFF);
    bf16*  w2f    = (bf16*)(ws + W2F_OFF);
    bf16*  w_outf = (bf16*)(ws + WOUTF_OFF);
    float* bnp    = (float*)(ws + BNP_OFF);

    hipLaunchKernelGGL(k_norm, dim3(256), dim3(256), 0, stream, x, xn);
    hipLaunchKernelGGL(k_pack, dim3(367), dim3(256), 0, stream,
                       w_in, w1, w2, w_out,
                       g_in, b_in, m_in, v_in, g1, b1, m1, v1,
                       g2, b2, m2, v2, g_out, b_out, m_out, v_out,
                       w_inf, w1f, w2f, w_outf, bnp);
    hipLaunchKernelGGL(k_s1, dim3(PTOT), dim3(256), 0, stream, xn, w_inf, bnp, a1);
    hipLaunchKernelGGL(k_s2, dim3(1152), dim3(256), 0, stream, w1f, a1, bnp, a2);
    hipLaunchKernelGGL(k_s34, dim3(256), dim3(256), 0, stream, a2, w2f, w_outf, bnp, out);
}

// Round 2
// 202.508 us; speedup vs baseline: 1.5572x; 1.5572x over previous
//
#include <hip/hip_runtime.h>

// Problem constants
#define BB   4
#define CC   144
#define HW   4096      // 64*64
#define PTOT 16384     // BB*HW
#define EPSB 1e-5f

typedef __bf16 bf16;
typedef __bf16 bf16x8 __attribute__((ext_vector_type(8)));
typedef float  f32x4  __attribute__((ext_vector_type(4)));
typedef unsigned short U16;
typedef unsigned int   U32;
typedef U16 u16x4 __attribute__((ext_vector_type(4)));
typedef U16 u16x8 __attribute__((ext_vector_type(8)));

#define MFMA __builtin_amdgcn_mfma_f32_16x16x32_bf16

// ---- workspace layout (bytes) ----
#define XN_OFF    0UL         // bf16 [16384][144] channel-last   4,718,592
#define A1_OFF    4718592UL   // bf16 [16384][25][64] pos,c-last  52,428,800
#define A2_OFF    57147392UL  // bf16 [16384][576]                18,874,368
#define WINF_OFF  76021760UL  // bf16 frag [4][5][64][8]          20,480
#define W1F_OFF   76042240UL  // bf16 frag [4][18][64][8]         73,728
#define W2F_OFF   76115968UL  // bf16 frag [4][18][64][8]         73,728
#define WOUTF_OFF 76189696UL  // bf16 frag [9][2][64][8]          18,432
#define BNP_OFF   76208128UL  // f32 [672]

// ------------------------------------------------------------------
// K1: L2 normalize over channel dim -> xn channel-last [p][144] bf16
// grid 256 (b*64+h), block 256 (64 w x 4 channel-quarters)
__global__ __launch_bounds__(256) void k_norm(const float* __restrict__ x,
                                              bf16* __restrict__ xn)
{
    __shared__ float red[4][64];
    int bh = blockIdx.x;
    int b = bh >> 6, h = bh & 63;
    int t = threadIdx.x, w = t & 63, cq = t >> 6;
    const float* px = x + ((size_t)b*CC)*HW + h*64 + w;
    float vals[36];
    float s = 0.f;
    #pragma unroll
    for (int i = 0; i < 36; i++) { float v = px[(size_t)(cq*36 + i)*HW]; vals[i] = v; s += v*v; }
    red[cq][w] = s;
    __syncthreads();
    float tot = red[0][w] + red[1][w] + red[2][w] + red[3][w];
    float inv = 1.f / fmaxf(sqrtf(tot), 1e-12f);
    U16* po = (U16*)(xn + ((size_t)(bh*64 + w))*144 + cq*36);
    #pragma unroll
    for (int k = 0; k < 9; k++) {
        u16x4 pk;
        #pragma unroll
        for (int r = 0; r < 4; r++) { bf16 v = (bf16)(vals[k*4+r]*inv); pk[r] = *(U16*)&v; }
        *(u16x4*)(po + k*4) = pk;
    }
}

// ------------------------------------------------------------------
// K2: pack weights into MFMA A-fragment order + fold BN params
// frag layout: F[mt][ks][lane][j] = W[o = mt*16+(lane&15)][k = ks*32+(lane>>4)*8+j]
__global__ __launch_bounds__(256) void k_pack(
    const float* __restrict__ w_in, const float* __restrict__ w1,
    const float* __restrict__ w2,   const float* __restrict__ w_out,
    const float* g_in, const float* b_in, const float* m_in, const float* v_in,
    const float* g1,   const float* b1,   const float* m1,   const float* v1,
    const float* g2,   const float* b2,   const float* m2,   const float* v2,
    const float* g_out,const float* b_out,const float* m_out,const float* v_out,
    bf16* w_inf, bf16* w1f, bf16* w2f, bf16* w_outf, float* bnp)
{
    int t = blockIdx.x*256 + threadIdx.x;
    if (t < 10240) {                       // w_inf: k = c, padded 144->160
        int e = t, j = e & 7, lane = (e >> 3) & 63, r = e >> 9;
        int ks = r % 5, mt = r / 5;
        int o = mt*16 + (lane & 15);
        int c = ks*32 + ((lane >> 4) << 3) + j;
        w_inf[e] = (c < 144) ? (bf16)w_in[o*144 + c] : (bf16)0.f;
    } else if (t < 47104) {                // w1f: K=576, k = ij*64 + c  (REORDERED)
        int e = t - 10240, j = e & 7, lane = (e >> 3) & 63, r = e >> 9;
        int ks = r % 18, mt = r / 18;
        int o = mt*16 + (lane & 15);
        int k = ks*32 + ((lane >> 4) << 3) + j;
        int ij = k >> 6, c = k & 63;
        w1f[e] = (bf16)w1[(o*64 + c)*9 + ij];
    } else if (t < 83968) {                // w2f: k = c2*9 + rs (matches a2 layout)
        int e = t - 47104, j = e & 7, lane = (e >> 3) & 63, r = e >> 9;
        int ks = r % 18, mt = r / 18;
        int o = mt*16 + (lane & 15);
        int k = ks*32 + ((lane >> 4) << 3) + j;
        w2f[e] = (bf16)w2[o*576 + k];
    } else if (t < 93184) {                // w_outf: M=144 (9 mt), K=64 (2 ks)
        int e = t - 83968, j = e & 7, lane = (e >> 3) & 63, r = e >> 9;
        int ks = r & 1, mt = r >> 1;
        int o = mt*16 + (lane & 15);
        int c = ks*32 + ((lane >> 4) << 3) + j;
        w_outf[e] = (bf16)w_out[o*64 + c];
    } else if (t < 93856) {                // BN fold: s = g*rsqrt(v+eps), t = b - m*s
        int i = t - 93184;
        const float *g, *bb, *mm, *vv; int c; bool is_t;
        if (i < 128)      { g=g_in; bb=b_in; mm=m_in; vv=v_in; c=i&63;        is_t=i>=64;  }
        else if (i < 256) { g=g1;   bb=b1;   mm=m1;   vv=v1;   c=(i-128)&63;  is_t=i>=192; }
        else if (i < 384) { g=g2;   bb=b2;   mm=m2;   vv=v2;   c=(i-256)&63;  is_t=i>=320; }
        else              { int ii=i-384; g=g_out; bb=b_out; mm=m_out; vv=v_out;
                            c = ii % 144; is_t = ii >= 144; }
        float s = g[c] * rsqrtf(vv[c] + EPSB);
        bnp[i] = is_t ? (bb[c] - mm[c]*s) : s;
    }
}

// ------------------------------------------------------------------
// K3: stage 1. GEMM per kp: Z1[o][p] = W_in @ (xn[p+delta] * xn[p]) over c.
// grid 1280 = 256 pos-tiles x 5 kp-groups; block 256 = 4 waves x 16 positions.
// All frags are direct 16B loads (channel-last xn); no LDS.
__global__ __launch_bounds__(256) void k_s1(const bf16* __restrict__ xn,
        const bf16* __restrict__ w_inf, const float* __restrict__ bnp,
        bf16* __restrict__ a1)
{
    int t = threadIdx.x;
    int wid = t >> 6, lane = t & 63, quad = lane >> 4, col16 = lane & 15;
    int tile = blockIdx.x & 255, kpg = blockIdx.x >> 8;
    int p = tile*64 + wid*16 + col16;
    int h = (p >> 6) & 63, w = p & 63;
    const bf16* xrow = xn + (size_t)p*144;

    // A-frags cached in registers (w_inf is tiny + L2-hot)
    bf16x8 af[4][5];
    #pragma unroll
    for (int mt = 0; mt < 4; mt++)
        #pragma unroll
        for (int ks = 0; ks < 5; ks++)
            af[mt][ks] = *(const bf16x8*)(w_inf + ((mt*5 + ks)*64 + lane)*8);

    // center fragments (K padded: ks=4, quad>=2 -> c>=144 -> zero)
    bf16x8 cfr[5];
    #pragma unroll
    for (int ks = 0; ks < 5; ks++) {
        bf16x8 z = {};
        cfr[ks] = (ks < 4 || quad < 2) ? *(const bf16x8*)(xrow + ks*32 + quad*8) : z;
    }
    // BN params for this lane's 16 output rows
    float sv[16], tv[16];
    #pragma unroll
    for (int mt = 0; mt < 4; mt++)
        #pragma unroll
        for (int r = 0; r < 4; r++) {
            int o = mt*16 + quad*4 + r;
            sv[mt*4+r] = bnp[o]; tv[mt*4+r] = bnp[64 + o];
        }

    int dh = kpg - 2;
    for (int kpl = 0; kpl < 5; kpl++) {
        int dw = kpl - 2;
        bool valid = ((unsigned)(h + dh) < 64u) && ((unsigned)(w + dw) < 64u);
        const bf16* nrow = xrow + (dh*64 + dw)*144;
        f32x4 acc[4] = {};
        #pragma unroll
        for (int ks = 0; ks < 5; ks++) {
            bf16x8 bfr = {};
            if (valid && (ks < 4 || quad < 2)) {
                bf16x8 nv = *(const bf16x8*)(nrow + ks*32 + quad*8);
                #pragma unroll
                for (int j = 0; j < 8; j++)
                    bfr[j] = (bf16)((float)nv[j] * (float)cfr[ks][j]);
            }
            #pragma unroll
            for (int mt = 0; mt < 4; mt++)
                acc[mt] = MFMA(af[mt][ks], bfr, acc[mt], 0, 0, 0);
        }
        int kp = kpg*5 + kpl;
        bf16* arow = a1 + (size_t)p*1600 + kp*64;
        #pragma unroll
        for (int mt = 0; mt < 4; mt++) {
            u16x4 pk;
            #pragma unroll
            for (int r = 0; r < 4; r++) {
                bf16 v = (bf16)fmaxf(acc[mt][r]*sv[mt*4+r] + tv[mt*4+r], 0.f);
                pk[r] = *(U16*)&v;
            }
            *(u16x4*)(arow + mt*16 + quad*4) = pk;   // 4 consecutive channels, 8B store
        }
    }
}

// ------------------------------------------------------------------
// K4: stage 2 GEMM M=64, K=576 (k=ij*64+c), N=147456 (n=p*9+rs).
// B-frag = contiguous 16B load from a1[p][LUT5[ij]+LUT5[rs]][c0]. No LDS, no gather.
// block 256 = 4 waves; wave = all 4 m-tiles x 2 n-tiles (32 cols); grid 1152.
__global__ __launch_bounds__(256) void k_s2(const bf16* __restrict__ w1f,
        const bf16* __restrict__ a1, const float* __restrict__ bnp,
        bf16* __restrict__ a2)
{
    int t = threadIdx.x;
    int wid = t >> 6, lane = t & 63, quad = lane >> 4, col16 = lane & 15;
    const int LUT5[9] = {0,1,2,5,6,7,10,11,12};
    int nA = blockIdx.x*128 + wid*32 + col16;
    int nB = nA + 16;
    int pA = nA / 9, rsA = nA - 9*pA;
    int pB = nB / 9, rsB = nB - 9*pB;
    U32 baseA = (U32)pA*1600 + (U32)LUT5[rsA]*64 + quad*8;
    U32 baseB = (U32)pB*1600 + (U32)LUT5[rsB]*64 + quad*8;

    f32x4 acc[4][2] = {};
    #pragma unroll
    for (int ks = 0; ks < 18; ks++) {
        const int ij = ks >> 1;
        const U32 off = (U32)(LUT5[ij]*64 + (ks & 1)*32);
        bf16x8 b0 = *(const bf16x8*)(a1 + baseA + off);
        bf16x8 b1 = *(const bf16x8*)(a1 + baseB + off);
        #pragma unroll
        for (int mt = 0; mt < 4; mt++) {
            bf16x8 afr = *(const bf16x8*)(w1f + ((mt*18 + ks)*64 + lane)*8);
            acc[mt][0] = MFMA(afr, b0, acc[mt][0], 0, 0, 0);
            acc[mt][1] = MFMA(afr, b1, acc[mt][1], 0, 0, 0);
        }
    }
    // epilogue: BN + ReLU -> a2[p*576 + o*9 + rs]
    U32 oA = (U32)pA*576 + (U32)rsA, oB = (U32)pB*576 + (U32)rsB;
    #pragma unroll
    for (int mt = 0; mt < 4; mt++) {
        #pragma unroll
        for (int r = 0; r < 4; r++) {
            int o = mt*16 + quad*4 + r;
            float s = bnp[128 + o], tt = bnp[192 + o];
            a2[oA + o*9] = (bf16)fmaxf(acc[mt][0][r]*s + tt, 0.f);
            a2[oB + o*9] = (bf16)fmaxf(acc[mt][1][r]*s + tt, 0.f);
        }
    }
}

// ------------------------------------------------------------------
// K5: stage 3 (64x576 per-position a2, N=64 cols) + BN/ReLU
//     -> LDS transpose -> stage 4 (144x64) + final BN -> fp32 out
// grid 256 (row blocks), block 256 (4 waves)
__global__ __launch_bounds__(256) void k_s34(const bf16* __restrict__ a2,
        const bf16* __restrict__ w2f, const bf16* __restrict__ w_outf,
        const float* __restrict__ bnp, float* __restrict__ out)
{
    __shared__ __align__(16) U16 v3[64*64];   // [col][cm]
    int t = threadIdx.x, wid = t >> 6, lane = t & 63, quad = lane >> 4, col16 = lane & 15;
    int p0 = blockIdx.x * 64;
    int b = p0 >> 12, hw0 = p0 & 4095;
    f32x4 acc[4] = {};
    for (int ks = 0; ks < 18; ks++) {
        bf16x8 afr = *(const bf16x8*)(w2f + ((wid*18 + ks)*64 + lane)*8);
        #pragma unroll
        for (int nt = 0; nt < 4; nt++) {
            int p = p0 + nt*16 + col16;
            bf16x8 bfr = *(const bf16x8*)(a2 + (size_t)p*576 + ks*32 + quad*8);
            acc[nt] = MFMA(afr, bfr, acc[nt], 0, 0, 0);
        }
    }
    #pragma unroll
    for (int nt = 0; nt < 4; nt++) {
        int colA = nt*16 + col16;
        #pragma unroll
        for (int r = 0; r < 4; r++) {
            int o = wid*16 + quad*4 + r;
            float s = bnp[256 + o], tt = bnp[320 + o];
            bf16 yb = (bf16)fmaxf(acc[nt][r]*s + tt, 0.f);
            v3[colA*64 + o] = *(U16*)&yb;
        }
    }
    __syncthreads();
    for (int mt = wid; mt < 9; mt += 4) {
        f32x4 accB[4] = {};
        #pragma unroll
        for (int ks = 0; ks < 2; ks++) {
            bf16x8 afr = *(const bf16x8*)(w_outf + ((mt*2 + ks)*64 + lane)*8);
            #pragma unroll
            for (int nt = 0; nt < 4; nt++) {
                bf16x8 bfr = *(const bf16x8*)&v3[(nt*16 + col16)*64 + ks*32 + quad*8];
                accB[nt] = MFMA(afr, bfr, accB[nt], 0, 0, 0);
            }
        }
        #pragma unroll
        for (int nt = 0; nt < 4; nt++) {
            #pragma unroll
            for (int r = 0; r < 4; r++) {
                int oc = mt*16 + quad*4 + r;
                float s = bnp[384 + oc], tt = bnp[528 + oc];
                out[((size_t)(b*144 + oc))*4096 + hw0 + nt*16 + col16] = accB[nt][r]*s + tt;
            }
        }
    }
}

// ------------------------------------------------------------------
extern "C" void kernel_launch(void* const* d_in, const int* in_sizes, int n_in,
                              void* d_out, int out_size, void* d_ws, size_t ws_size,
                              hipStream_t stream)
{
    const float* x     = (const float*)d_in[0];
    const float* w_in  = (const float*)d_in[1];
    const float* g_in  = (const float*)d_in[2];
    const float* b_in  = (const float*)d_in[3];
    const float* m_in  = (const float*)d_in[4];
    const float* v_in  = (const float*)d_in[5];
    const float* w1    = (const float*)d_in[6];
    const float* g1    = (const float*)d_in[7];
    const float* b1    = (const float*)d_in[8];
    const float* m1    = (const float*)d_in[9];
    const float* v1    = (const float*)d_in[10];
    const float* w2    = (const float*)d_in[11];
    const float* g2    = (const float*)d_in[12];
    const float* b2    = (const float*)d_in[13];
    const float* m2    = (const float*)d_in[14];
    const float* v2    = (const float*)d_in[15];
    const float* w_out = (const float*)d_in[16];
    const float* g_out = (const float*)d_in[17];
    const float* b_out = (const float*)d_in[18];
    const float* m_out = (const float*)d_in[19];
    const float* v_out = (const float*)d_in[20];
    float* out = (float*)d_out;

    char* ws = (char*)d_ws;
    bf16*  xn     = (bf16*)(ws + XN_OFF);
    bf16*  a1     = (bf16*)(ws + A1_OFF);
    bf16*  a2     = (bf16*)(ws + A2_OFF);
    bf16*  w_inf  = (bf16*)(ws + WINF_OFF);
    bf16*  w1f    = (bf16*)(ws + W1F_OFF);
    bf16*  w2f    = (bf16*)(ws + W2F_OFF);
    bf16*  w_outf = (bf16*)(ws + WOUTF_OFF);
    float* bnp    = (float*)(ws + BNP_OFF);

    hipLaunchKernelGGL(k_norm, dim3(256), dim3(256), 0, stream, x, xn);
    hipLaunchKernelGGL(k_pack, dim3(367), dim3(256), 0, stream,
                       w_in, w1, w2, w_out,
                       g_in, b_in, m_in, v_in, g1, b1, m1, v1,
                       g2, b2, m2, v2, g_out, b_out, m_out, v_out,
                       w_inf, w1f, w2f, w_outf, bnp);
    hipLaunchKernelGGL(k_s1, dim3(1280), dim3(256), 0, stream, xn, w_inf, bnp, a1);
    hipLaunchKernelGGL(k_s2, dim3(1152), dim3(256), 0, stream, w1f, a1, bnp, a2);
    hipLaunchKernelGGL(k_s34, dim3(256), dim3(256), 0, stream, a2, w2f, w_outf, bnp, out);
}

// Round 3
// 201.238 us; speedup vs baseline: 1.5671x; 1.0063x over previous
//
#include <hip/hip_runtime.h>

// Problem constants
#define BB   4
#define CC   144
#define HW   4096      // 64*64
#define PTOT 16384     // BB*HW
#define EPSB 1e-5f

typedef __bf16 bf16;
typedef __bf16 bf16x8 __attribute__((ext_vector_type(8)));
typedef float  f32x4  __attribute__((ext_vector_type(4)));
typedef unsigned short U16;
typedef unsigned int   U32;
typedef U16 u16x4 __attribute__((ext_vector_type(4)));
typedef U16 u16x8 __attribute__((ext_vector_type(8)));

#define MFMA __builtin_amdgcn_mfma_f32_16x16x32_bf16

// ---- workspace layout (bytes) ----
#define XN_OFF    0UL         // bf16 [16384][144] channel-last   4,718,592
#define A1_OFF    4718592UL   // bf16 [16384][25][64] pos,c-last  52,428,800
#define A2_OFF    57147392UL  // bf16 [16384][576]                18,874,368
#define WINF_OFF  76021760UL  // bf16 frag [4][5][64][8]          20,480
#define W1F_OFF   76042240UL  // bf16 frag [4][18][64][8]         73,728
#define W2F_OFF   76115968UL  // bf16 frag [4][18][64][8]         73,728
#define WOUTF_OFF 76189696UL  // bf16 frag [9][2][64][8]          18,432
#define BNP_OFF   76208128UL  // f32 [672]

// ------------------------------------------------------------------
// K1: L2 normalize over channel dim -> xn channel-last [p][144] bf16
__global__ __launch_bounds__(256) void k_norm(const float* __restrict__ x,
                                              bf16* __restrict__ xn)
{
    __shared__ float red[4][64];
    int bh = blockIdx.x;
    int b = bh >> 6, h = bh & 63;
    int t = threadIdx.x, w = t & 63, cq = t >> 6;
    const float* px = x + ((size_t)b*CC)*HW + h*64 + w;
    float vals[36];
    float s = 0.f;
    #pragma unroll
    for (int i = 0; i < 36; i++) { float v = px[(size_t)(cq*36 + i)*HW]; vals[i] = v; s += v*v; }
    red[cq][w] = s;
    __syncthreads();
    float tot = red[0][w] + red[1][w] + red[2][w] + red[3][w];
    float inv = 1.f / fmaxf(sqrtf(tot), 1e-12f);
    U16* po = (U16*)(xn + ((size_t)(bh*64 + w))*144 + cq*36);
    #pragma unroll
    for (int k = 0; k < 9; k++) {
        u16x4 pk;
        #pragma unroll
        for (int r = 0; r < 4; r++) { bf16 v = (bf16)(vals[k*4+r]*inv); pk[r] = *(U16*)&v; }
        *(u16x4*)(po + k*4) = pk;
    }
}

// ------------------------------------------------------------------
// K2: pack weights into MFMA A-fragment order + fold BN params
__global__ __launch_bounds__(256) void k_pack(
    const float* __restrict__ w_in, const float* __restrict__ w1,
    const float* __restrict__ w2,   const float* __restrict__ w_out,
    const float* g_in, const float* b_in, const float* m_in, const float* v_in,
    const float* g1,   const float* b1,   const float* m1,   const float* v1,
    const float* g2,   const float* b2,   const float* m2,   const float* v2,
    const float* g_out,const float* b_out,const float* m_out,const float* v_out,
    bf16* w_inf, bf16* w1f, bf16* w2f, bf16* w_outf, float* bnp)
{
    int t = blockIdx.x*256 + threadIdx.x;
    if (t < 10240) {                       // w_inf: k = c, padded 144->160
        int e = t, j = e & 7, lane = (e >> 3) & 63, r = e >> 9;
        int ks = r % 5, mt = r / 5;
        int o = mt*16 + (lane & 15);
        int c = ks*32 + ((lane >> 4) << 3) + j;
        w_inf[e] = (c < 144) ? (bf16)w_in[o*144 + c] : (bf16)0.f;
    } else if (t < 47104) {                // w1f: K=576, k = ij*64 + c
        int e = t - 10240, j = e & 7, lane = (e >> 3) & 63, r = e >> 9;
        int ks = r % 18, mt = r / 18;
        int o = mt*16 + (lane & 15);
        int k = ks*32 + ((lane >> 4) << 3) + j;
        int ij = k >> 6, c = k & 63;
        w1f[e] = (bf16)w1[(o*64 + c)*9 + ij];
    } else if (t < 83968) {                // w2f: k = c2*9 + rs
        int e = t - 47104, j = e & 7, lane = (e >> 3) & 63, r = e >> 9;
        int ks = r % 18, mt = r / 18;
        int o = mt*16 + (lane & 15);
        int k = ks*32 + ((lane >> 4) << 3) + j;
        w2f[e] = (bf16)w2[o*576 + k];
    } else if (t < 93184) {                // w_outf: M=144 (9 mt), K=64 (2 ks)
        int e = t - 83968, j = e & 7, lane = (e >> 3) & 63, r = e >> 9;
        int ks = r & 1, mt = r >> 1;
        int o = mt*16 + (lane & 15);
        int c = ks*32 + ((lane >> 4) << 3) + j;
        w_outf[e] = (bf16)w_out[o*64 + c];
    } else if (t < 93856) {                // BN fold
        int i = t - 93184;
        const float *g, *bb, *mm, *vv; int c; bool is_t;
        if (i < 128)      { g=g_in; bb=b_in; mm=m_in; vv=v_in; c=i&63;        is_t=i>=64;  }
        else if (i < 256) { g=g1;   bb=b1;   mm=m1;   vv=v1;   c=(i-128)&63;  is_t=i>=192; }
        else if (i < 384) { g=g2;   bb=b2;   mm=m2;   vv=v2;   c=(i-256)&63;  is_t=i>=320; }
        else              { int ii=i-384; g=g_out; bb=b_out; mm=m_out; vv=v_out;
                            c = ii % 144; is_t = ii >= 144; }
        float s = g[c] * rsqrtf(vv[c] + EPSB);
        bnp[i] = is_t ? (bb[c] - mm[c]*s) : s;
    }
}

// ------------------------------------------------------------------
// K3: stage 1. Block = one image row (64 positions) x one dh (kpg).
// Zero-padded LDS neighbor row (stride 168 els = 336 B: conflict-free b128).
// grid 1280 = 256 tiles x 5 kpg; block 256 = 4 waves x 16 positions.
#define LROW 168
__global__ __launch_bounds__(256) void k_s1(const bf16* __restrict__ xn,
        const bf16* __restrict__ w_inf, const float* __restrict__ bnp,
        bf16* __restrict__ a1)
{
    __shared__ __align__(16) U16 nb[68*LROW];   // padded neighbor row, 22848 B
    int t = threadIdx.x;
    int wid = t >> 6, lane = t & 63, quad = lane >> 4, col16 = lane & 15;
    int tile = blockIdx.x & 255, kpg = blockIdx.x >> 8;
    int dh = kpg - 2;
    int h = tile & 63;
    int p = tile*64 + wid*16 + col16;
    int w = p & 63;
    const bf16* xrow = xn + (size_t)p*144;

    // zero whole buffer (pads + possibly-invalid row)
    {
        u16x8 z = {};
        for (int i = t; i < 68*LROW/8; i += 256) *(u16x8*)&nb[i*8] = z;
    }
    __syncthreads();
    int hr = h + dh;
    if ((unsigned)hr < 64u) {
        const U16* grow = (const U16*)(xn + ((size_t)(tile + dh) * 64) * 144);
        for (int i = t; i < 1152; i += 256) {
            int wcol = i / 18, k16 = i - 18*wcol;
            u16x8 v = *(const u16x8*)(grow + wcol*144 + k16*8);
            *(u16x8*)&nb[(2 + wcol)*LROW + k16*8] = v;
        }
    }
    // register-resident A-frags, center frags, BN (loads overlap staging)
    bf16x8 af[4][5];
    #pragma unroll
    for (int mt = 0; mt < 4; mt++)
        #pragma unroll
        for (int ks = 0; ks < 5; ks++)
            af[mt][ks] = *(const bf16x8*)(w_inf + ((mt*5 + ks)*64 + lane)*8);
    bf16x8 cfr[5];
    #pragma unroll
    for (int ks = 0; ks < 5; ks++) {
        bf16x8 z = {};
        cfr[ks] = (ks < 4 || quad < 2) ? *(const bf16x8*)(xrow + ks*32 + quad*8) : z;
    }
    float sv[16], tv[16];
    #pragma unroll
    for (int mt = 0; mt < 4; mt++)
        #pragma unroll
        for (int r = 0; r < 4; r++) {
            int o = mt*16 + quad*4 + r;
            sv[mt*4+r] = bnp[o]; tv[mt*4+r] = bnp[64 + o];
        }
    __syncthreads();

    for (int kpl = 0; kpl < 5; kpl++) {
        const bf16* lrow = (const bf16*)&nb[(w + kpl)*LROW];   // row w+dw+2 = w+kpl
        f32x4 acc[4] = {};
        #pragma unroll
        for (int ks = 0; ks < 5; ks++) {
            bf16x8 nv = *(const bf16x8*)(lrow + ks*32 + quad*8);
            bf16x8 bfr;
            #pragma unroll
            for (int j = 0; j < 8; j++)
                bfr[j] = (bf16)((float)nv[j] * (float)cfr[ks][j]);
            #pragma unroll
            for (int mt = 0; mt < 4; mt++)
                acc[mt] = MFMA(af[mt][ks], bfr, acc[mt], 0, 0, 0);
        }
        int kp = kpg*5 + kpl;
        bf16* arow = a1 + (size_t)p*1600 + kp*64;
        #pragma unroll
        for (int mt = 0; mt < 4; mt++) {
            u16x4 pk;
            #pragma unroll
            for (int r = 0; r < 4; r++) {
                bf16 v = (bf16)fmaxf(acc[mt][r]*sv[mt*4+r] + tv[mt*4+r], 0.f);
                pk[r] = *(U16*)&v;
            }
            *(u16x4*)(arow + mt*16 + quad*4) = pk;
        }
    }
}

// ------------------------------------------------------------------
// K4: stage 2 GEMM M=64, K=576 (k=ij*64+c), N=147456 (n=p*9+rs).
// Wave = 2 m-tiles x 4 n-tiles (M split across block halves); register
// double-buffered A+B frags (depth-1 prefetch, 16 indep MFMAs/stage).
// grid 1152 = 576 col-groups x 2 m-halves.
__global__ __launch_bounds__(256) void k_s2(const bf16* __restrict__ w1f,
        const bf16* __restrict__ a1, const float* __restrict__ bnp,
        bf16* __restrict__ a2)
{
    int t = threadIdx.x;
    int wid = t >> 6, lane = t & 63, quad = lane >> 4, col16 = lane & 15;
    const int LUT5[9] = {0,1,2,5,6,7,10,11,12};
    int bid = blockIdx.x;
    int cg = bid % 576, mth = bid / 576;
    int n0 = cg*256 + wid*64;
    U32 baseB[4], oB[4];
    #pragma unroll
    for (int nt = 0; nt < 4; nt++) {
        int n = n0 + nt*16 + col16;
        int pp = n / 9, rs = n - 9*pp;
        baseB[nt] = (U32)pp*1600 + (U32)LUT5[rs]*64 + quad*8;
        oB[nt]    = (U32)pp*576 + (U32)rs + (U32)mth*288;
    }
    const bf16* w1g = w1f + (size_t)(mth*2)*18*64*8;
    f32x4 acc[2][4] = {};
    bf16x8 bb[2][4], aa[2][2];
    #pragma unroll
    for (int nt = 0; nt < 4; nt++) bb[0][nt] = *(const bf16x8*)(a1 + baseB[nt]);
    #pragma unroll
    for (int m = 0; m < 2; m++)   aa[0][m]  = *(const bf16x8*)(w1g + ((m*18)*64 + lane)*8);

    #pragma unroll
    for (int ks = 0; ks < 18; ks++) {
        int cur = ks & 1, nxt = cur ^ 1;
        if (ks < 17) {
            int k2 = ks + 1, ij = k2 >> 1;
            U32 off = (U32)(LUT5[ij]*64 + (k2 & 1)*32);
            #pragma unroll
            for (int nt = 0; nt < 4; nt++) bb[nxt][nt] = *(const bf16x8*)(a1 + baseB[nt] + off);
            #pragma unroll
            for (int m = 0; m < 2; m++)   aa[nxt][m]  = *(const bf16x8*)(w1g + ((m*18 + k2)*64 + lane)*8);
        }
        #pragma unroll
        for (int m = 0; m < 2; m++)
            #pragma unroll
            for (int nt = 0; nt < 4; nt++)
                acc[m][nt] = MFMA(aa[cur][m], bb[cur][nt], acc[m][nt], 0, 0, 0);
    }
    // epilogue: BN + ReLU -> a2[p*576 + o*9 + rs]
    #pragma unroll
    for (int m = 0; m < 2; m++) {
        #pragma unroll
        for (int r = 0; r < 4; r++) {
            int o = mth*32 + m*16 + quad*4 + r;
            float s = bnp[128 + o], tt = bnp[192 + o];
            U32 o9 = (U32)(m*16 + quad*4 + r)*9;
            #pragma unroll
            for (int nt = 0; nt < 4; nt++)
                a2[oB[nt] + o9] = (bf16)fmaxf(acc[m][nt][r]*s + tt, 0.f);
        }
    }
}

// ------------------------------------------------------------------
// K5: stage 3 (64x576, 32 cols/block) + BN/ReLU -> LDS transpose ->
//     stage 4 (144x64) + final BN -> fp32 out. grid 512.
__global__ __launch_bounds__(256) void k_s34(const bf16* __restrict__ a2,
        const bf16* __restrict__ w2f, const bf16* __restrict__ w_outf,
        const float* __restrict__ bnp, float* __restrict__ out)
{
    __shared__ __align__(16) U16 v3[32*64];   // [col][cm]
    int t = threadIdx.x, wid = t >> 6, lane = t & 63, quad = lane >> 4, col16 = lane & 15;
    int p0 = blockIdx.x * 32;
    int b = p0 >> 12, hw0 = p0 & 4095;
    f32x4 acc[2] = {};
    #pragma unroll
    for (int ks = 0; ks < 18; ks++) {
        bf16x8 afr = *(const bf16x8*)(w2f + ((wid*18 + ks)*64 + lane)*8);
        #pragma unroll
        for (int nt = 0; nt < 2; nt++) {
            int p = p0 + nt*16 + col16;
            bf16x8 bfr = *(const bf16x8*)(a2 + (size_t)p*576 + ks*32 + quad*8);
            acc[nt] = MFMA(afr, bfr, acc[nt], 0, 0, 0);
        }
    }
    #pragma unroll
    for (int nt = 0; nt < 2; nt++) {
        int colA = nt*16 + col16;
        #pragma unroll
        for (int r = 0; r < 4; r++) {
            int o = wid*16 + quad*4 + r;
            float s = bnp[256 + o], tt = bnp[320 + o];
            bf16 yb = (bf16)fmaxf(acc[nt][r]*s + tt, 0.f);
            v3[colA*64 + o] = *(U16*)&yb;
        }
    }
    __syncthreads();
    for (int mt = wid; mt < 9; mt += 4) {
        f32x4 accB[2] = {};
        #pragma unroll
        for (int ks = 0; ks < 2; ks++) {
            bf16x8 afr = *(const bf16x8*)(w_outf + ((mt*2 + ks)*64 + lane)*8);
            #pragma unroll
            for (int nt = 0; nt < 2; nt++) {
                bf16x8 bfr = *(const bf16x8*)&v3[(nt*16 + col16)*64 + ks*32 + quad*8];
                accB[nt] = MFMA(afr, bfr, accB[nt], 0, 0, 0);
            }
        }
        #pragma unroll
        for (int nt = 0; nt < 2; nt++) {
            #pragma unroll
            for (int r = 0; r < 4; r++) {
                int oc = mt*16 + quad*4 + r;
                float s = bnp[384 + oc], tt = bnp[528 + oc];
                out[((size_t)(b*144 + oc))*4096 + hw0 + nt*16 + col16] = accB[nt][r]*s + tt;
            }
        }
    }
}

// ------------------------------------------------------------------
extern "C" void kernel_launch(void* const* d_in, const int* in_sizes, int n_in,
                              void* d_out, int out_size, void* d_ws, size_t ws_size,
                              hipStream_t stream)
{
    const float* x     = (const float*)d_in[0];
    const float* w_in  = (const float*)d_in[1];
    const float* g_in  = (const float*)d_in[2];
    const float* b_in  = (const float*)d_in[3];
    const float* m_in  = (const float*)d_in[4];
    const float* v_in  = (const float*)d_in[5];
    const float* w1    = (const float*)d_in[6];
    const float* g1    = (const float*)d_in[7];
    const float* b1    = (const float*)d_in[8];
    const float* m1    = (const float*)d_in[9];
    const float* v1    = (const float*)d_in[10];
    const float* w2    = (const float*)d_in[11];
    const float* g2    = (const float*)d_in[12];
    const float* b2    = (const float*)d_in[13];
    const float* m2    = (const float*)d_in[14];
    const float* v2    = (const float*)d_in[15];
    const float* w_out = (const float*)d_in[16];
    const float* g_out = (const float*)d_in[17];
    const float* b_out = (const float*)d_in[18];
    const float* m_out = (const float*)d_in[19];
    const float* v_out = (const float*)d_in[20];
    float* out = (float*)d_out;

    char* ws = (char*)d_ws;
    bf16*  xn     = (bf16*)(ws + XN_OFF);
    bf16*  a1     = (bf16*)(ws + A1_OFF);
    bf16*  a2     = (bf16*)(ws + A2_OFF);
    bf16*  w_inf  = (bf16*)(ws + WINF_OFF);
    bf16*  w1f    = (bf16*)(ws + W1F_OFF);
    bf16*  w2f    = (bf16*)(ws + W2F_OFF);
    bf16*  w_outf = (bf16*)(ws + WOUTF_OFF);
    float* bnp    = (float*)(ws + BNP_OFF);

    hipLaunchKernelGGL(k_norm, dim3(256), dim3(256), 0, stream, x, xn);
    hipLaunchKernelGGL(k_pack, dim3(367), dim3(256), 0, stream,
                       w_in, w1, w2, w_out,
                       g_in, b_in, m_in, v_in, g1, b1, m1, v1,
                       g2, b2, m2, v2, g_out, b_out, m_out, v_out,
                       w_inf, w1f, w2f, w_outf, bnp);
    hipLaunchKernelGGL(k_s1, dim3(1280), dim3(256), 0, stream, xn, w_inf, bnp, a1);
    hipLaunchKernelGGL(k_s2, dim3(1152), dim3(256), 0, stream, w1f, a1, bnp, a2);
    hipLaunchKernelGGL(k_s34, dim3(512), dim3(256), 0, stream, a2, w2f, w_outf, bnp, out);
}

// Round 5
// 186.665 us; speedup vs baseline: 1.6894x; 1.0781x over previous
//
#include <hip/hip_runtime.h>

// Problem constants
#define BB   4
#define CC   144
#define HW   4096      // 64*64
#define PTOT 16384     // BB*HW
#define EPSB 1e-5f

typedef __bf16 bf16;
typedef __bf16 bf16x8 __attribute__((ext_vector_type(8)));
typedef float  f32x4  __attribute__((ext_vector_type(4)));
typedef unsigned short U16;
typedef unsigned int   U32;
typedef U16 u16x4 __attribute__((ext_vector_type(4)));
typedef U16 u16x8 __attribute__((ext_vector_type(8)));

#define MFMA __builtin_amdgcn_mfma_f32_16x16x32_bf16

// ---- workspace layout (bytes) ----
#define XN_OFF    0UL         // bf16 [16384][144] channel-last   4,718,592
#define A1_OFF    4718592UL   // bf16 [16384][25][64] pos,c-last  52,428,800
#define A2_OFF    57147392UL  // bf16 [16384][576]                18,874,368
#define WINF_OFF  76021760UL  // bf16 frag [4][5][64][8]          20,480
#define W1F_OFF   76042240UL  // bf16 frag [4][18][64][8]         73,728
#define W2F_OFF   76115968UL  // bf16 frag [4][18][64][8]         73,728
#define WOUTF_OFF 76189696UL  // bf16 frag [9][2][64][8]          18,432
#define BNP_OFF   76208128UL  // f32 [672]

// ------------------------------------------------------------------
// K1: L2 normalize over channel dim -> xn channel-last [p][144] bf16
__global__ __launch_bounds__(256) void k_norm(const float* __restrict__ x,
                                              bf16* __restrict__ xn)
{
    __shared__ float red[4][64];
    int bh = blockIdx.x;
    int b = bh >> 6, h = bh & 63;
    int t = threadIdx.x, w = t & 63, cq = t >> 6;
    const float* px = x + ((size_t)b*CC)*HW + h*64 + w;
    float vals[36];
    float s = 0.f;
    #pragma unroll
    for (int i = 0; i < 36; i++) { float v = px[(size_t)(cq*36 + i)*HW]; vals[i] = v; s += v*v; }
    red[cq][w] = s;
    __syncthreads();
    float tot = red[0][w] + red[1][w] + red[2][w] + red[3][w];
    float inv = 1.f / fmaxf(sqrtf(tot), 1e-12f);
    U16* po = (U16*)(xn + ((size_t)(bh*64 + w))*144 + cq*36);
    #pragma unroll
    for (int k = 0; k < 9; k++) {
        u16x4 pk;
        #pragma unroll
        for (int r = 0; r < 4; r++) { bf16 v = (bf16)(vals[k*4+r]*inv); pk[r] = *(U16*)&v; }
        *(u16x4*)(po + k*4) = pk;
    }
}

// ------------------------------------------------------------------
// K2: pack weights into MFMA A-fragment order + fold BN params
__global__ __launch_bounds__(256) void k_pack(
    const float* __restrict__ w_in, const float* __restrict__ w1,
    const float* __restrict__ w2,   const float* __restrict__ w_out,
    const float* g_in, const float* b_in, const float* m_in, const float* v_in,
    const float* g1,   const float* b1,   const float* m1,   const float* v1,
    const float* g2,   const float* b2,   const float* m2,   const float* v2,
    const float* g_out,const float* b_out,const float* m_out,const float* v_out,
    bf16* w_inf, bf16* w1f, bf16* w2f, bf16* w_outf, float* bnp)
{
    int t = blockIdx.x*256 + threadIdx.x;
    if (t < 10240) {                       // w_inf: k = c, padded 144->160
        int e = t, j = e & 7, lane = (e >> 3) & 63, r = e >> 9;
        int ks = r % 5, mt = r / 5;
        int o = mt*16 + (lane & 15);
        int c = ks*32 + ((lane >> 4) << 3) + j;
        w_inf[e] = (c < 144) ? (bf16)w_in[o*144 + c] : (bf16)0.f;
    } else if (t < 47104) {                // w1f: K=576, k = ij*64 + c
        int e = t - 10240, j = e & 7, lane = (e >> 3) & 63, r = e >> 9;
        int ks = r % 18, mt = r / 18;
        int o = mt*16 + (lane & 15);
        int k = ks*32 + ((lane >> 4) << 3) + j;
        int ij = k >> 6, c = k & 63;
        w1f[e] = (bf16)w1[(o*64 + c)*9 + ij];
    } else if (t < 83968) {                // w2f: k = c2*9 + rs
        int e = t - 47104, j = e & 7, lane = (e >> 3) & 63, r = e >> 9;
        int ks = r % 18, mt = r / 18;
        int o = mt*16 + (lane & 15);
        int k = ks*32 + ((lane >> 4) << 3) + j;
        w2f[e] = (bf16)w2[o*576 + k];
    } else if (t < 93184) {                // w_outf: M=144 (9 mt), K=64 (2 ks)
        int e = t - 83968, j = e & 7, lane = (e >> 3) & 63, r = e >> 9;
        int ks = r & 1, mt = r >> 1;
        int o = mt*16 + (lane & 15);
        int c = ks*32 + ((lane >> 4) << 3) + j;
        w_outf[e] = (bf16)w_out[o*64 + c];
    } else if (t < 93856) {                // BN fold
        int i = t - 93184;
        const float *g, *bb, *mm, *vv; int c; bool is_t;
        if (i < 128)      { g=g_in; bb=b_in; mm=m_in; vv=v_in; c=i&63;        is_t=i>=64;  }
        else if (i < 256) { g=g1;   bb=b1;   mm=m1;   vv=v1;   c=(i-128)&63;  is_t=i>=192; }
        else if (i < 384) { g=g2;   bb=b2;   mm=m2;   vv=v2;   c=(i-256)&63;  is_t=i>=320; }
        else              { int ii=i-384; g=g_out; bb=b_out; mm=m_out; vv=v_out;
                            c = ii % 144; is_t = ii >= 144; }
        float s = g[c] * rsqrtf(vv[c] + EPSB);
        bnp[i] = is_t ? (bb[c] - mm[c]*s) : s;
    }
}

// ------------------------------------------------------------------
// K3: stage 1. Block = one image row (64 positions) x one dh (kpg).
// Zero-padded LDS neighbor row (stride 168 els = 336 B: conflict-free b128).
#define LROW 168
__global__ __launch_bounds__(256) void k_s1(const bf16* __restrict__ xn,
        const bf16* __restrict__ w_inf, const float* __restrict__ bnp,
        bf16* __restrict__ a1)
{
    __shared__ __align__(16) U16 nb[68*LROW];   // padded neighbor row, 22848 B
    int t = threadIdx.x;
    int wid = t >> 6, lane = t & 63, quad = lane >> 4, col16 = lane & 15;
    int tile = blockIdx.x & 255, kpg = blockIdx.x >> 8;
    int dh = kpg - 2;
    int h = tile & 63;
    int p = tile*64 + wid*16 + col16;
    int w = p & 63;
    const bf16* xrow = xn + (size_t)p*144;

    {
        u16x8 z = {};
        for (int i = t; i < 68*LROW/8; i += 256) *(u16x8*)&nb[i*8] = z;
    }
    __syncthreads();
    int hr = h + dh;
    if ((unsigned)hr < 64u) {
        const U16* grow = (const U16*)(xn + ((size_t)(tile + dh) * 64) * 144);
        for (int i = t; i < 1152; i += 256) {
            int wcol = i / 18, k16 = i - 18*wcol;
            u16x8 v = *(const u16x8*)(grow + wcol*144 + k16*8);
            *(u16x8*)&nb[(2 + wcol)*LROW + k16*8] = v;
        }
    }
    bf16x8 af[4][5];
    #pragma unroll
    for (int mt = 0; mt < 4; mt++)
        #pragma unroll
        for (int ks = 0; ks < 5; ks++)
            af[mt][ks] = *(const bf16x8*)(w_inf + ((mt*5 + ks)*64 + lane)*8);
    bf16x8 cfr[5];
    #pragma unroll
    for (int ks = 0; ks < 5; ks++) {
        bf16x8 z = {};
        cfr[ks] = (ks < 4 || quad < 2) ? *(const bf16x8*)(xrow + ks*32 + quad*8) : z;
    }
    f32x4 sv[4], tv[4];
    #pragma unroll
    for (int mt = 0; mt < 4; mt++) {
        sv[mt] = *(const f32x4*)&bnp[mt*16 + quad*4];
        tv[mt] = *(const f32x4*)&bnp[64 + mt*16 + quad*4];
    }
    __syncthreads();

    for (int kpl = 0; kpl < 5; kpl++) {
        const bf16* lrow = (const bf16*)&nb[(w + kpl)*LROW];
        f32x4 acc[4] = {};
        #pragma unroll
        for (int ks = 0; ks < 5; ks++) {
            bf16x8 nv = *(const bf16x8*)(lrow + ks*32 + quad*8);
            bf16x8 bfr;
            #pragma unroll
            for (int j = 0; j < 8; j++)
                bfr[j] = (bf16)((float)nv[j] * (float)cfr[ks][j]);
            #pragma unroll
            for (int mt = 0; mt < 4; mt++)
                acc[mt] = MFMA(af[mt][ks], bfr, acc[mt], 0, 0, 0);
        }
        int kp = kpg*5 + kpl;
        bf16* arow = a1 + (size_t)p*1600 + kp*64;
        #pragma unroll
        for (int mt = 0; mt < 4; mt++) {
            u16x4 pk;
            #pragma unroll
            for (int r = 0; r < 4; r++) {
                bf16 v = (bf16)fmaxf(acc[mt][r]*sv[mt][r] + tv[mt][r], 0.f);
                pk[r] = *(U16*)&v;
            }
            *(u16x4*)(arow + mt*16 + quad*4) = pk;
        }
    }
}

// ------------------------------------------------------------------
// K4: stage 2 GEMM M=64, K=576 (k=ij*64+c), N=147456 (n=p*9+rs).
// Full M per block. Wave = 4mt x 2nt (32 cols).
// Register pipeline: B ring-4/lookahead-3, A ring-3/lookahead-2
// (lookahead strictly < ring depth: prefetch slot != consume slot).
// XCD swizzle: contiguous n-range per XCD. grid 1152.
__global__ __launch_bounds__(256) void k_s2(const bf16* __restrict__ w1f,
        const bf16* __restrict__ a1, const float* __restrict__ bnp,
        bf16* __restrict__ a2)
{
    int t = threadIdx.x;
    int wid = t >> 6, lane = t & 63, quad = lane >> 4, col16 = lane & 15;
    const int LUT5[9] = {0,1,2,5,6,7,10,11,12};
    U32 koff[18];
    #pragma unroll
    for (int ks = 0; ks < 18; ks++) koff[ks] = (U32)(LUT5[ks >> 1]*64 + (ks & 1)*32);

    int bid = blockIdx.x;
    bid = (bid & 7)*144 + (bid >> 3);      // 1152 = 8 XCD-chunks x 144
    int nA = bid*128 + wid*32 + col16;
    int nB = nA + 16;
    int pA = nA / 9, rsA = nA - 9*pA;
    int pB = nB / 9, rsB = nB - 9*pB;
    U32 baseA = (U32)pA*1600 + (U32)LUT5[rsA]*64 + quad*8;
    U32 baseB = (U32)pB*1600 + (U32)LUT5[rsB]*64 + quad*8;

    bf16x8 bb[4][2], aa[3][4];
    #pragma unroll
    for (int d = 0; d < 3; d++) {
        bb[d][0] = *(const bf16x8*)(a1 + baseA + koff[d]);
        bb[d][1] = *(const bf16x8*)(a1 + baseB + koff[d]);
    }
    #pragma unroll
    for (int d = 0; d < 2; d++)
        #pragma unroll
        for (int mt = 0; mt < 4; mt++)
            aa[d][mt] = *(const bf16x8*)(w1f + ((mt*18 + d)*64 + lane)*8);

    f32x4 acc[4][2] = {};
    #pragma unroll
    for (int ks = 0; ks < 18; ks++) {
        if (ks + 3 < 18) {                     // B prefetch: slot (ks+3)&3 != ks&3
            bb[(ks+3) & 3][0] = *(const bf16x8*)(a1 + baseA + koff[ks+3]);
            bb[(ks+3) & 3][1] = *(const bf16x8*)(a1 + baseB + koff[ks+3]);
        }
        if (ks + 2 < 18) {                     // A prefetch: slot (ks+2)%3 != ks%3
            #pragma unroll
            for (int mt = 0; mt < 4; mt++)
                aa[(ks+2) % 3][mt] = *(const bf16x8*)(w1f + ((mt*18 + ks+2)*64 + lane)*8);
        }
        #pragma unroll
        for (int mt = 0; mt < 4; mt++) {
            acc[mt][0] = MFMA(aa[ks % 3][mt], bb[ks & 3][0], acc[mt][0], 0, 0, 0);
            acc[mt][1] = MFMA(aa[ks % 3][mt], bb[ks & 3][1], acc[mt][1], 0, 0, 0);
        }
    }
    // epilogue: BN + ReLU -> a2[p*576 + o*9 + rs]
    U32 oA = (U32)pA*576 + (U32)rsA, oB = (U32)pB*576 + (U32)rsB;
    #pragma unroll
    for (int mt = 0; mt < 4; mt++) {
        #pragma unroll
        for (int r = 0; r < 4; r++) {
            int o = mt*16 + quad*4 + r;
            float s = bnp[128 + o], tt = bnp[192 + o];
            a2[oA + o*9] = (bf16)fmaxf(acc[mt][0][r]*s + tt, 0.f);
            a2[oB + o*9] = (bf16)fmaxf(acc[mt][1][r]*s + tt, 0.f);
        }
    }
}

// ------------------------------------------------------------------
// K5: stage 3 (64x576, 32 cols/block; B ring-4/la-3, A ring-3/la-2)
//     + BN/ReLU -> LDS transpose -> stage 4 (144x64) + final BN -> fp32 out.
__global__ __launch_bounds__(256) void k_s34(const bf16* __restrict__ a2,
        const bf16* __restrict__ w2f, const bf16* __restrict__ w_outf,
        const float* __restrict__ bnp, float* __restrict__ out)
{
    __shared__ __align__(16) U16 v3[32*64];   // [col][cm]
    int t = threadIdx.x, wid = t >> 6, lane = t & 63, quad = lane >> 4, col16 = lane & 15;
    int p0 = blockIdx.x * 32;
    int b = p0 >> 12, hw0 = p0 & 4095;
    const bf16* bptr0 = a2 + (size_t)(p0 + col16)*576 + quad*8;
    const bf16* bptr1 = a2 + (size_t)(p0 + 16 + col16)*576 + quad*8;

    bf16x8 bb[4][2], aa[3];
    #pragma unroll
    for (int d = 0; d < 3; d++) {
        bb[d][0] = *(const bf16x8*)(bptr0 + d*32);
        bb[d][1] = *(const bf16x8*)(bptr1 + d*32);
    }
    #pragma unroll
    for (int d = 0; d < 2; d++)
        aa[d] = *(const bf16x8*)(w2f + ((wid*18 + d)*64 + lane)*8);

    f32x4 acc[2] = {};
    #pragma unroll
    for (int ks = 0; ks < 18; ks++) {
        if (ks + 3 < 18) {
            bb[(ks+3) & 3][0] = *(const bf16x8*)(bptr0 + (ks+3)*32);
            bb[(ks+3) & 3][1] = *(const bf16x8*)(bptr1 + (ks+3)*32);
        }
        if (ks + 2 < 18)
            aa[(ks+2) % 3] = *(const bf16x8*)(w2f + ((wid*18 + ks+2)*64 + lane)*8);
        acc[0] = MFMA(aa[ks % 3], bb[ks & 3][0], acc[0], 0, 0, 0);
        acc[1] = MFMA(aa[ks % 3], bb[ks & 3][1], acc[1], 0, 0, 0);
    }
    #pragma unroll
    for (int nt = 0; nt < 2; nt++) {
        int colA = nt*16 + col16;
        #pragma unroll
        for (int r = 0; r < 4; r++) {
            int o = wid*16 + quad*4 + r;
            float s = bnp[256 + o], tt = bnp[320 + o];
            bf16 yb = (bf16)fmaxf(acc[nt][r]*s + tt, 0.f);
            v3[colA*64 + o] = *(U16*)&yb;
        }
    }
    __syncthreads();
    for (int mt = wid; mt < 9; mt += 4) {
        f32x4 accB[2] = {};
        #pragma unroll
        for (int ks = 0; ks < 2; ks++) {
            bf16x8 afr = *(const bf16x8*)(w_outf + ((mt*2 + ks)*64 + lane)*8);
            #pragma unroll
            for (int nt = 0; nt < 2; nt++) {
                bf16x8 bfr = *(const bf16x8*)&v3[(nt*16 + col16)*64 + ks*32 + quad*8];
                accB[nt] = MFMA(afr, bfr, accB[nt], 0, 0, 0);
            }
        }
        #pragma unroll
        for (int nt = 0; nt < 2; nt++) {
            #pragma unroll
            for (int r = 0; r < 4; r++) {
                int oc = mt*16 + quad*4 + r;
                float s = bnp[384 + oc], tt = bnp[528 + oc];
                out[((size_t)(b*144 + oc))*4096 + hw0 + nt*16 + col16] = accB[nt][r]*s + tt;
            }
        }
    }
}

// ------------------------------------------------------------------
extern "C" void kernel_launch(void* const* d_in, const int* in_sizes, int n_in,
                              void* d_out, int out_size, void* d_ws, size_t ws_size,
                              hipStream_t stream)
{
    const float* x     = (const float*)d_in[0];
    const float* w_in  = (const float*)d_in[1];
    const float* g_in  = (const float*)d_in[2];
    const float* b_in  = (const float*)d_in[3];
    const float* m_in  = (const float*)d_in[4];
    const float* v_in  = (const float*)d_in[5];
    const float* w1    = (const float*)d_in[6];
    const float* g1    = (const float*)d_in[7];
    const float* b1    = (const float*)d_in[8];
    const float* m1    = (const float*)d_in[9];
    const float* v1    = (const float*)d_in[10];
    const float* w2    = (const float*)d_in[11];
    const float* g2    = (const float*)d_in[12];
    const float* b2    = (const float*)d_in[13];
    const float* m2    = (const float*)d_in[14];
    const float* v2    = (const float*)d_in[15];
    const float* w_out = (const float*)d_in[16];
    const float* g_out = (const float*)d_in[17];
    const float* b_out = (const float*)d_in[18];
    const float* m_out = (const float*)d_in[19];
    const float* v_out = (const float*)d_in[20];
    float* out = (float*)d_out;

    char* ws = (char*)d_ws;
    bf16*  xn     = (bf16*)(ws + XN_OFF);
    bf16*  a1     = (bf16*)(ws + A1_OFF);
    bf16*  a2     = (bf16*)(ws + A2_OFF);
    bf16*  w_inf  = (bf16*)(ws + WINF_OFF);
    bf16*  w1f    = (bf16*)(ws + W1F_OFF);
    bf16*  w2f    = (bf16*)(ws + W2F_OFF);
    bf16*  w_outf = (bf16*)(ws + WOUTF_OFF);
    float* bnp    = (float*)(ws + BNP_OFF);

    hipLaunchKernelGGL(k_norm, dim3(256), dim3(256), 0, stream, x, xn);
    hipLaunchKernelGGL(k_pack, dim3(367), dim3(256), 0, stream,
                       w_in, w1, w2, w_out,
                       g_in, b_in, m_in, v_in, g1, b1, m1, v1,
                       g2, b2, m2, v2, g_out, b_out, m_out, v_out,
                       w_inf, w1f, w2f, w_outf, bnp);
    hipLaunchKernelGGL(k_s1, dim3(1280), dim3(256), 0, stream, xn, w_inf, bnp, a1);
    hipLaunchKernelGGL(k_s2, dim3(1152), dim3(256), 0, stream, w1f, a1, bnp, a2);
    hipLaunchKernelGGL(k_s34, dim3(512), dim3(256), 0, stream, a2, w2f, w_outf, bnp, out);
}

// Round 6
// 162.688 us; speedup vs baseline: 1.9384x; 1.1474x over previous
//
#include <hip/hip_runtime.h>

// Problem constants
#define BB   4
#define CC   144
#define HW   4096      // 64*64
#define PTOT 16384     // BB*HW
#define EPSB 1e-5f

typedef __bf16 bf16;
typedef __bf16 bf16x8 __attribute__((ext_vector_type(8)));
typedef float  f32x4  __attribute__((ext_vector_type(4)));
typedef unsigned short U16;
typedef unsigned int   U32;
typedef U16 u16x4 __attribute__((ext_vector_type(4)));
typedef U16 u16x8 __attribute__((ext_vector_type(8)));

#define MFMA __builtin_amdgcn_mfma_f32_16x16x32_bf16

// ---- workspace layout (bytes) ----
#define XN_OFF    0UL         // bf16 [16384][144] channel-last   4,718,592
#define A1_OFF    4718592UL   // bf16 [16384][25][64] pos,c-last  52,428,800
#define A2_OFF    57147392UL  // bf16 [16384][9][64] (k=rs*64+c2) 18,874,368
#define WINF_OFF  76021760UL  // bf16 frag [4][5][64][8]          20,480
#define W1F_OFF   76042240UL  // bf16 frag [4][18][64][8]         73,728
#define W2F_OFF   76115968UL  // bf16 frag [4][18][64][8]         73,728
#define WOUTF_OFF 76189696UL  // bf16 frag [9][2][64][8]          18,432
#define BNP_OFF   76208128UL  // f32 [672]

// ------------------------------------------------------------------
// K1: L2 normalize over channel dim -> xn channel-last [p][144] bf16
__global__ __launch_bounds__(256) void k_norm(const float* __restrict__ x,
                                              bf16* __restrict__ xn)
{
    __shared__ float red[4][64];
    int bh = blockIdx.x;
    int b = bh >> 6, h = bh & 63;
    int t = threadIdx.x, w = t & 63, cq = t >> 6;
    const float* px = x + ((size_t)b*CC)*HW + h*64 + w;
    float vals[36];
    float s = 0.f;
    #pragma unroll
    for (int i = 0; i < 36; i++) { float v = px[(size_t)(cq*36 + i)*HW]; vals[i] = v; s += v*v; }
    red[cq][w] = s;
    __syncthreads();
    float tot = red[0][w] + red[1][w] + red[2][w] + red[3][w];
    float inv = 1.f / fmaxf(sqrtf(tot), 1e-12f);
    U16* po = (U16*)(xn + ((size_t)(bh*64 + w))*144 + cq*36);
    #pragma unroll
    for (int k = 0; k < 9; k++) {
        u16x4 pk;
        #pragma unroll
        for (int r = 0; r < 4; r++) { bf16 v = (bf16)(vals[k*4+r]*inv); pk[r] = *(U16*)&v; }
        *(u16x4*)(po + k*4) = pk;
    }
}

// ------------------------------------------------------------------
// K2: pack weights into MFMA A-fragment order + fold BN params
__global__ __launch_bounds__(256) void k_pack(
    const float* __restrict__ w_in, const float* __restrict__ w1,
    const float* __restrict__ w2,   const float* __restrict__ w_out,
    const float* g_in, const float* b_in, const float* m_in, const float* v_in,
    const float* g1,   const float* b1,   const float* m1,   const float* v1,
    const float* g2,   const float* b2,   const float* m2,   const float* v2,
    const float* g_out,const float* b_out,const float* m_out,const float* v_out,
    bf16* w_inf, bf16* w1f, bf16* w2f, bf16* w_outf, float* bnp)
{
    int t = blockIdx.x*256 + threadIdx.x;
    if (t < 10240) {                       // w_inf: k = c, padded 144->160
        int e = t, j = e & 7, lane = (e >> 3) & 63, r = e >> 9;
        int ks = r % 5, mt = r / 5;
        int o = mt*16 + (lane & 15);
        int c = ks*32 + ((lane >> 4) << 3) + j;
        w_inf[e] = (c < 144) ? (bf16)w_in[o*144 + c] : (bf16)0.f;
    } else if (t < 47104) {                // w1f: K=576, k = ij*64 + c
        int e = t - 10240, j = e & 7, lane = (e >> 3) & 63, r = e >> 9;
        int ks = r % 18, mt = r / 18;
        int o = mt*16 + (lane & 15);
        int k = ks*32 + ((lane >> 4) << 3) + j;
        int ij = k >> 6, c = k & 63;
        w1f[e] = (bf16)w1[(o*64 + c)*9 + ij];
    } else if (t < 83968) {                // w2f: k = rs*64 + c2 (matches a2 [p][rs][c2])
        int e = t - 47104, j = e & 7, lane = (e >> 3) & 63, r = e >> 9;
        int ks = r % 18, mt = r / 18;
        int o = mt*16 + (lane & 15);
        int k = ks*32 + ((lane >> 4) << 3) + j;
        int rs = k >> 6, c2 = k & 63;
        w2f[e] = (bf16)w2[o*576 + c2*9 + rs];
    } else if (t < 93184) {                // w_outf: M=144 (9 mt), K=64 (2 ks)
        int e = t - 83968, j = e & 7, lane = (e >> 3) & 63, r = e >> 9;
        int ks = r & 1, mt = r >> 1;
        int o = mt*16 + (lane & 15);
        int c = ks*32 + ((lane >> 4) << 3) + j;
        w_outf[e] = (bf16)w_out[o*64 + c];
    } else if (t < 93856) {                // BN fold
        int i = t - 93184;
        const float *g, *bb, *mm, *vv; int c; bool is_t;
        if (i < 128)      { g=g_in; bb=b_in; mm=m_in; vv=v_in; c=i&63;        is_t=i>=64;  }
        else if (i < 256) { g=g1;   bb=b1;   mm=m1;   vv=v1;   c=(i-128)&63;  is_t=i>=192; }
        else if (i < 384) { g=g2;   bb=b2;   mm=m2;   vv=v2;   c=(i-256)&63;  is_t=i>=320; }
        else              { int ii=i-384; g=g_out; bb=b_out; mm=m_out; vv=v_out;
                            c = ii % 144; is_t = ii >= 144; }
        float s = g[c] * rsqrtf(vv[c] + EPSB);
        bnp[i] = is_t ? (bb[c] - mm[c]*s) : s;
    }
}

// ------------------------------------------------------------------
// K3: stage 1. Block = one image row (64 positions) x one dh (kpg).
// Zero-padded LDS neighbor row (stride 168 els = 336 B).
#define LROW 168
__global__ __launch_bounds__(256) void k_s1(const bf16* __restrict__ xn,
        const bf16* __restrict__ w_inf, const float* __restrict__ bnp,
        bf16* __restrict__ a1)
{
    __shared__ __align__(16) U16 nb[68*LROW];   // 22848 B
    int t = threadIdx.x;
    int wid = t >> 6, lane = t & 63, quad = lane >> 4, col16 = lane & 15;
    int tile = blockIdx.x & 255, kpg = blockIdx.x >> 8;
    int dh = kpg - 2;
    int h = tile & 63;
    int p = tile*64 + wid*16 + col16;
    int w = p & 63;
    const bf16* xrow = xn + (size_t)p*144;

    int hr = h + dh;
    u16x8 z = {};
    if ((unsigned)hr < 64u) {
        // zero only pads: w-pad rows {0,1,66,67} fully + tail cols 144..167 of data rows
        for (int i = t; i < 84; i += 256) {          // 4 rows * 21 chunks
            int r = i / 21, cc = i % 21;
            int row = (r < 2) ? r : 64 + r;
            *(u16x8*)&nb[row*LROW + cc*8] = z;
        }
        for (int i = t; i < 192; i += 256) {         // 64 rows * 3 tail chunks
            int row = 2 + i / 3, cc = 18 + (i % 3);
            *(u16x8*)&nb[row*LROW + cc*8] = z;
        }
        const U16* grow = (const U16*)(xn + ((size_t)(tile + dh) * 64) * 144);
        for (int i = t; i < 1152; i += 256) {
            int wcol = i / 18, k16 = i - 18*wcol;
            u16x8 v = *(const u16x8*)(grow + wcol*144 + k16*8);
            *(u16x8*)&nb[(2 + wcol)*LROW + k16*8] = v;
        }
    } else {
        for (int i = t; i < 68*LROW/8; i += 256) *(u16x8*)&nb[i*8] = z;
    }
    bf16x8 af[4][5];
    #pragma unroll
    for (int mt = 0; mt < 4; mt++)
        #pragma unroll
        for (int ks = 0; ks < 5; ks++)
            af[mt][ks] = *(const bf16x8*)(w_inf + ((mt*5 + ks)*64 + lane)*8);
    bf16x8 cfr[5];
    #pragma unroll
    for (int ks = 0; ks < 5; ks++) {
        bf16x8 zz = {};
        cfr[ks] = (ks < 4 || quad < 2) ? *(const bf16x8*)(xrow + ks*32 + quad*8) : zz;
    }
    f32x4 sv[4], tv[4];
    #pragma unroll
    for (int mt = 0; mt < 4; mt++) {
        sv[mt] = *(const f32x4*)&bnp[mt*16 + quad*4];
        tv[mt] = *(const f32x4*)&bnp[64 + mt*16 + quad*4];
    }
    __syncthreads();

    for (int kpl = 0; kpl < 5; kpl++) {
        const bf16* lrow = (const bf16*)&nb[(w + kpl)*LROW];
        f32x4 acc[4] = {};
        #pragma unroll
        for (int ks = 0; ks < 5; ks++) {
            bf16x8 nv = *(const bf16x8*)(lrow + ks*32 + quad*8);
            bf16x8 bfr;
            #pragma unroll
            for (int j = 0; j < 8; j++)
                bfr[j] = (bf16)((float)nv[j] * (float)cfr[ks][j]);
            #pragma unroll
            for (int mt = 0; mt < 4; mt++)
                acc[mt] = MFMA(af[mt][ks], bfr, acc[mt], 0, 0, 0);
        }
        int kp = kpg*5 + kpl;
        bf16* arow = a1 + (size_t)p*1600 + kp*64;
        #pragma unroll
        for (int mt = 0; mt < 4; mt++) {
            u16x4 pk;
            #pragma unroll
            for (int r = 0; r < 4; r++) {
                bf16 v = (bf16)fmaxf(acc[mt][r]*sv[mt][r] + tv[mt][r], 0.f);
                pk[r] = *(U16*)&v;
            }
            *(u16x4*)(arow + mt*16 + quad*4) = pk;
        }
    }
}

// ------------------------------------------------------------------
// K4: stage 2 GEMM M=64, K=576 (k=ij*64+c), N=147456 (n=p*9+rs).
// Block stages its 16 consecutive a1 rows (contiguous 51200 B) into LDS
// with 16B-group bank swizzle (raw p/kp strides are 0 mod 32 banks).
// Wave = 2 mt x 4 nt. A (w1f) from global L2, ring-2. grid 1152, 3 blk/CU.
__global__ __launch_bounds__(256) void k_s2(const bf16* __restrict__ w1f,
        const bf16* __restrict__ a1, const float* __restrict__ bnp,
        bf16* __restrict__ a2)
{
    __shared__ __align__(16) U16 Bs[16*1600];   // 51200 B
    int t = threadIdx.x;
    int wid = t >> 6, lane = t & 63, quad = lane >> 4, col16 = lane & 15;
    int nhalf = wid >> 1, mhalf = wid & 1;
    const int LUT5[9] = {0,1,2,5,6,7,10,11,12};
    int bid = blockIdx.x;
    bid = (bid & 7)*144 + (bid >> 3);      // XCD swizzle
    int n0 = bid*128;
    int pf = n0 / 9;

    // ---- stage 16 a1 rows -> LDS (coalesced, deep queue, swizzled) ----
    const U16* gsrc = (const U16*)(a1 + (size_t)pf*1600);
    u16x8 sreg[13];
    #pragma unroll
    for (int it = 0; it < 13; it++) {
        int i = it*256 + t;
        if (i < 3200) sreg[it] = *(const u16x8*)(gsrc + i*8);
    }
    #pragma unroll
    for (int it = 0; it < 13; it++) {
        int i = it*256 + t;
        if (i < 3200) {
            int grp = i & 7, rem = i >> 3;
            int kpidx = rem % 25, prow = rem / 25;
            int dst = prow*1600 + kpidx*64 + (((grp + kpidx*3 + prow*4) & 7) << 3);
            *(u16x8*)&Bs[dst] = sreg[it];
        }
    }

    int pd4[4], lrs[4]; U32 oN[4];
    #pragma unroll
    for (int nt = 0; nt < 4; nt++) {
        int n = n0 + nhalf*64 + nt*16 + col16;
        int pp = n / 9, rs = n - 9*pp;
        pd4[nt] = pp - pf; lrs[nt] = LUT5[rs];
        oN[nt] = (U32)pp*576 + (U32)rs*64;
    }
    bf16x8 aa[2][2];
    #pragma unroll
    for (int m = 0; m < 2; m++)
        aa[0][m] = *(const bf16x8*)(w1f + (((mhalf*2 + m)*18)*64 + lane)*8);
    __syncthreads();

    f32x4 acc[2][4] = {};
    #pragma unroll
    for (int ks = 0; ks < 18; ks++) {
        int ij = ks >> 1, half = ks & 1;
        if (ks + 1 < 18) {                 // A ring-2 / lookahead-1
            #pragma unroll
            for (int m = 0; m < 2; m++)
                aa[(ks+1) & 1][m] = *(const bf16x8*)(w1f + (((mhalf*2 + m)*18 + ks + 1)*64 + lane)*8);
        }
        bf16x8 bfr[4];
        #pragma unroll
        for (int nt = 0; nt < 4; nt++) {
            int kpidx = LUT5[ij] + lrs[nt];
            int off = pd4[nt]*1600 + kpidx*64 + (((half*4 + quad + kpidx*3 + pd4[nt]*4) & 7) << 3);
            bfr[nt] = *(const bf16x8*)&Bs[off];
        }
        #pragma unroll
        for (int m = 0; m < 2; m++)
            #pragma unroll
            for (int nt = 0; nt < 4; nt++)
                acc[m][nt] = MFMA(aa[ks & 1][m], bfr[nt], acc[m][nt], 0, 0, 0);
    }
    // epilogue: BN + ReLU -> a2[p][rs][c2] (contiguous u16x4 stores)
    #pragma unroll
    for (int m = 0; m < 2; m++) {
        int ob = (mhalf*2 + m)*16 + quad*4;
        f32x4 s = *(const f32x4*)&bnp[128 + ob];
        f32x4 tt = *(const f32x4*)&bnp[192 + ob];
        #pragma unroll
        for (int nt = 0; nt < 4; nt++) {
            u16x4 pk;
            #pragma unroll
            for (int r = 0; r < 4; r++) {
                bf16 v = (bf16)fmaxf(acc[m][nt][r]*s[r] + tt[r], 0.f);
                pk[r] = *(U16*)&v;
            }
            *(u16x4*)(a2 + oN[nt] + ob) = pk;
        }
    }
}

// ------------------------------------------------------------------
// K5: stage 3 (64x576, 32 cols/block; a2 chunk staged to LDS swizzled)
//     + BN/ReLU -> swizzled v3 -> stage 4 (144x64) + final BN -> fp32 out.
__global__ __launch_bounds__(256) void k_s34(const bf16* __restrict__ a2,
        const bf16* __restrict__ w2f, const bf16* __restrict__ w_outf,
        const float* __restrict__ bnp, float* __restrict__ out)
{
    __shared__ __align__(16) U16 As[32*576];  // 36864 B
    __shared__ __align__(16) U16 v3[32*64];   // 4096 B
    int t = threadIdx.x, wid = t >> 6, lane = t & 63, quad = lane >> 4, col16 = lane & 15;
    int p0 = blockIdx.x * 32;
    int b = p0 >> 12, hw0 = p0 & 4095;

    // stage 32 a2 rows (contiguous 36864 B) -> LDS, swizzled
    const U16* gsrc = (const U16*)(a2 + (size_t)p0*576);
    u16x8 sreg[9];
    #pragma unroll
    for (int it = 0; it < 9; it++) sreg[it] = *(const u16x8*)(gsrc + (it*256 + t)*8);
    #pragma unroll
    for (int it = 0; it < 9; it++) {
        int i = it*256 + t;
        int c = i % 72, pr = i / 72;
        int dst = pr*576 + (c >> 3)*64 + ((((c & 7) + pr) & 7) << 3);
        *(u16x8*)&As[dst] = sreg[it];
    }
    bf16x8 aa[2];
    aa[0] = *(const bf16x8*)(w2f + ((wid*18)*64 + lane)*8);
    __syncthreads();

    f32x4 acc[2] = {};
    #pragma unroll
    for (int ks = 0; ks < 18; ks++) {
        if (ks + 1 < 18)
            aa[(ks+1) & 1] = *(const bf16x8*)(w2f + ((wid*18 + ks + 1)*64 + lane)*8);
        #pragma unroll
        for (int nt = 0; nt < 2; nt++) {
            int p = nt*16 + col16;
            int c = ks*4 + quad;
            int off = p*576 + (c >> 3)*64 + ((((c & 7) + p) & 7) << 3);
            bf16x8 bfr = *(const bf16x8*)&As[off];
            acc[nt] = MFMA(aa[ks & 1], bfr, acc[nt], 0, 0, 0);
        }
    }
    #pragma unroll
    for (int nt = 0; nt < 2; nt++) {
        int colA = nt*16 + col16;
        #pragma unroll
        for (int r = 0; r < 4; r++) {
            int o = wid*16 + quad*4 + r;
            float s = bnp[256 + o], tt = bnp[320 + o];
            bf16 yb = (bf16)fmaxf(acc[nt][r]*s + tt, 0.f);
            v3[colA*64 + (((o >> 3) + colA) & 7)*8 + (o & 7)] = *(U16*)&yb;
        }
    }
    __syncthreads();
    for (int mt = wid; mt < 9; mt += 4) {
        f32x4 accB[2] = {};
        #pragma unroll
        for (int ks = 0; ks < 2; ks++) {
            bf16x8 afr = *(const bf16x8*)(w_outf + ((mt*2 + ks)*64 + lane)*8);
            #pragma unroll
            for (int nt = 0; nt < 2; nt++) {
                int colA = nt*16 + col16;
                int g = ks*4 + quad;
                bf16x8 bfr = *(const bf16x8*)&v3[colA*64 + (((g) + colA) & 7)*8];
                accB[nt] = MFMA(afr, bfr, accB[nt], 0, 0, 0);
            }
        }
        #pragma unroll
        for (int nt = 0; nt < 2; nt++) {
            #pragma unroll
            for (int r = 0; r < 4; r++) {
                int oc = mt*16 + quad*4 + r;
                float s = bnp[384 + oc], tt = bnp[528 + oc];
                out[((size_t)(b*144 + oc))*4096 + hw0 + nt*16 + col16] = accB[nt][r]*s + tt;
            }
        }
    }
}

// ------------------------------------------------------------------
extern "C" void kernel_launch(void* const* d_in, const int* in_sizes, int n_in,
                              void* d_out, int out_size, void* d_ws, size_t ws_size,
                              hipStream_t stream)
{
    const float* x     = (const float*)d_in[0];
    const float* w_in  = (const float*)d_in[1];
    const float* g_in  = (const float*)d_in[2];
    const float* b_in  = (const float*)d_in[3];
    const float* m_in  = (const float*)d_in[4];
    const float* v_in  = (const float*)d_in[5];
    const float* w1    = (const float*)d_in[6];
    const float* g1    = (const float*)d_in[7];
    const float* b1    = (const float*)d_in[8];
    const float* m1    = (const float*)d_in[9];
    const float* v1    = (const float*)d_in[10];
    const float* w2    = (const float*)d_in[11];
    const float* g2    = (const float*)d_in[12];
    const float* b2    = (const float*)d_in[13];
    const float* m2    = (const float*)d_in[14];
    const float* v2    = (const float*)d_in[15];
    const float* w_out = (const float*)d_in[16];
    const float* g_out = (const float*)d_in[17];
    const float* b_out = (const float*)d_in[18];
    const float* m_out = (const float*)d_in[19];
    const float* v_out = (const float*)d_in[20];
    float* out = (float*)d_out;

    char* ws = (char*)d_ws;
    bf16*  xn     = (bf16*)(ws + XN_OFF);
    bf16*  a1     = (bf16*)(ws + A1_OFF);
    bf16*  a2     = (bf16*)(ws + A2_OFF);
    bf16*  w_inf  = (bf16*)(ws + WINF_OFF);
    bf16*  w1f    = (bf16*)(ws + W1F_OFF);
    bf16*  w2f    = (bf16*)(ws + W2F_OFF);
    bf16*  w_outf = (bf16*)(ws + WOUTF_OFF);
    float* bnp    = (float*)(ws + BNP_OFF);

    hipLaunchKernelGGL(k_norm, dim3(256), dim3(256), 0, stream, x, xn);
    hipLaunchKernelGGL(k_pack, dim3(367), dim3(256), 0, stream,
                       w_in, w1, w2, w_out,
                       g_in, b_in, m_in, v_in, g1, b1, m1, v1,
                       g2, b2, m2, v2, g_out, b_out, m_out, v_out,
                       w_inf, w1f, w2f, w_outf, bnp);
    hipLaunchKernelGGL(k_s1, dim3(1280), dim3(256), 0, stream, xn, w_inf, bnp, a1);
    hipLaunchKernelGGL(k_s2, dim3(1152), dim3(256), 0, stream, w1f, a1, bnp, a2);
    hipLaunchKernelGGL(k_s34, dim3(512), dim3(256), 0, stream, a2, w2f, w_outf, bnp, out);
}